// Round 1
// baseline (700.768 us; speedup 1.0000x reference)
//
#include <hip/hip_runtime.h>
#include <hip/hip_bf16.h>
#include <math.h>

// Problem constants (from reference)
#define BATCH   32
#define NBLK    128
#define BLOCK_T 16
#define HEADS   16
#define DHEAD   128
#define HID     2048
#define FFN     8192
#define KV_LEN  2048

// ---------------------------------------------------------------------------
// RoPE cos/sin table: [KV_LEN][64]  (freq index i = lane, covers both halves)
// ---------------------------------------------------------------------------
__global__ void rope_table_kernel(float* __restrict__ ct, float* __restrict__ st) {
    int s = blockIdx.x;          // 0..2047
    int i = threadIdx.x;         // 0..63
    float inv = powf(10000.0f, -(float)i / 64.0f);
    float ang = (float)s * inv;
    ct[s * 64 + i] = cosf(ang);
    st[s * 64 + i] = sinf(ang);
}

// ---------------------------------------------------------------------------
// emb[b][c] = embed_tokens[ids[b]][c] + embed_positions[pos[b]][c]
// ---------------------------------------------------------------------------
__global__ void emb_kernel(const int* __restrict__ ids, const int* __restrict__ pos,
                           const float* __restrict__ et, const float* __restrict__ ep,
                           float* __restrict__ emb) {
    int b = blockIdx.x;
    int id = ids[b], p = pos[b];
    const float4* a = (const float4*)(et + (size_t)id * HID);
    const float4* d = (const float4*)(ep + (size_t)p * HID);
    float4* o = (float4*)(emb + (size_t)b * HID);
    for (int c = threadIdx.x; c < HID / 4; c += 256) {
        float4 x = a[c], y = d[c];
        o[c] = make_float4(x.x + y.x, x.y + y.y, x.z + y.z, x.w + y.w);
    }
}

// ---------------------------------------------------------------------------
// Split-K skinny GEMM: X[32][K] @ W[K][N] -> P[K/BK][32][N] (partials)
// block = 256 threads, thread owns 2 consecutive columns, all 32 batch rows.
// W rows streamed coalesced; X chunk staged transposed in LDS (broadcast reads).
// ---------------------------------------------------------------------------
template <int BK>
__global__ __launch_bounds__(256) void gemm_partial(
    const float* __restrict__ X, const float* __restrict__ W,
    float* __restrict__ P, int K, int N) {
    __shared__ float xs[BK][36];     // row stride 144 B = 16B aligned, depads banks
    const int tid = threadIdx.x;
    const int k0  = blockIdx.y * BK;
    const int j   = blockIdx.x * 512 + tid * 2;

    #pragma unroll
    for (int t = tid; t < 32 * BK; t += 256) {
        int bb = t / BK, ii = t % BK;          // consecutive t -> consecutive ii (coalesced)
        xs[ii][bb] = X[bb * K + k0 + ii];
    }
    __syncthreads();

    float acc[32][2];
    #pragma unroll
    for (int bb = 0; bb < 32; ++bb) { acc[bb][0] = 0.f; acc[bb][1] = 0.f; }

    const float* wp = W + (size_t)k0 * N + j;
    for (int ii = 0; ii < BK; ++ii) {
        const float2 w = *reinterpret_cast<const float2*>(wp + (size_t)ii * N);
        #pragma unroll
        for (int g = 0; g < 8; ++g) {
            const float4 xv = *reinterpret_cast<const float4*>(&xs[ii][g * 4]);
            acc[4 * g + 0][0] += xv.x * w.x; acc[4 * g + 0][1] += xv.x * w.y;
            acc[4 * g + 1][0] += xv.y * w.x; acc[4 * g + 1][1] += xv.y * w.y;
            acc[4 * g + 2][0] += xv.z * w.x; acc[4 * g + 2][1] += xv.z * w.y;
            acc[4 * g + 3][0] += xv.w * w.x; acc[4 * g + 3][1] += xv.w * w.y;
        }
    }

    float* pp = P + ((size_t)blockIdx.y * 32) * N + j;
    #pragma unroll
    for (int bb = 0; bb < 32; ++bb) {
        *reinterpret_cast<float2*>(pp + (size_t)bb * N) = make_float2(acc[bb][0], acc[bb][1]);
    }
}

// ---------------------------------------------------------------------------
// Reduce split-K partials: out[idx] = sum_c P[c][idx] (+ addsrc[idx])
// ---------------------------------------------------------------------------
__global__ void reduce_kernel(const float* __restrict__ P, int nch, int total,
                              float* __restrict__ out, const float* __restrict__ addsrc) {
    int idx = blockIdx.x * 256 + threadIdx.x;
    if (idx >= total) return;
    float s = 0.f;
    for (int c = 0; c < nch; ++c) s += P[(size_t)c * total + idx];
    if (addsrc) s += addsrc[idx];
    out[idx] = s;
}

// ---------------------------------------------------------------------------
// Reduce Wq partials + apply RoPE at positions[b] -> q[32][2048]
// thread owns (b, h, i) pair; rotates (i, i+64).
// ---------------------------------------------------------------------------
__global__ void reduce_rope_q_kernel(const float* __restrict__ P, int nch,
                                     const int* __restrict__ positions,
                                     const float* __restrict__ ct, const float* __restrict__ st,
                                     float* __restrict__ qout) {
    int idx = blockIdx.x * 256 + threadIdx.x;   // 32*16*64 = 32768 threads
    int i = idx & 63, hh = (idx >> 6) & 15, b = idx >> 10;
    int base = b * HID + hh * DHEAD;
    float q1 = 0.f, q2 = 0.f;
    for (int c = 0; c < nch; ++c) {
        q1 += P[(size_t)c * (BATCH * HID) + base + i];
        q2 += P[(size_t)c * (BATCH * HID) + base + 64 + i];
    }
    int pos = positions[b];
    float co = ct[pos * 64 + i], si = st[pos * 64 + i];
    qout[base + i]      = q1 * co - q2 * si;
    qout[base + 64 + i] = q1 * si + q2 * co;
}

// ---------------------------------------------------------------------------
// Paged decode attention. One block per (b,h); 4 waves stride tokens by 4.
// lane i holds dims {i, i+64} (RoPE pair is lane-local). Online softmax per
// wave, LDS combine. Manual 1-deep pipeline on the token loop.
// ---------------------------------------------------------------------------
__global__ __launch_bounds__(256) void attn_kernel(
    const float* __restrict__ q, const float* __restrict__ kv,
    const int* __restrict__ block_tables, const int* __restrict__ context_lens,
    const float* __restrict__ ct, const float* __restrict__ st,
    float* __restrict__ attn_out) {
    const int b = blockIdx.x >> 4, h = blockIdx.x & 15;
    const int wave = threadIdx.x >> 6, lane = threadIdx.x & 63;
    const int ctx = context_lens[b];
    const int qbase = b * HID + h * DHEAD;
    const float q1 = q[qbase + lane], q2 = q[qbase + 64 + lane];

    float m = -INFINITY, l = 0.f, a1 = 0.f, a2 = 0.f;

    auto kbase = [&](int s) -> const float* {
        int blk = block_tables[b * NBLK + (s >> 4)];
        return kv + (size_t)blk * 65536 + (size_t)(s & 15) * 2048 + h * DHEAD;
    };

    int s = wave;
    if (s < ctx) {
        const float* kp = kbase(s);
        float k1 = kp[lane], k2 = kp[64 + lane];
        float v1 = kp[32768 + lane], v2 = kp[32768 + 64 + lane];
        float c = ct[s * 64 + lane], sn = st[s * 64 + lane];
        for (;;) {
            int s2 = s + 4;
            bool more = s2 < ctx;
            int sp = more ? s2 : s;                 // safe re-read when done
            const float* kp2 = kbase(sp);
            float nk1 = kp2[lane], nk2 = kp2[64 + lane];
            float nv1 = kp2[32768 + lane], nv2 = kp2[32768 + 64 + lane];
            float nc = ct[sp * 64 + lane], nsn = st[sp * 64 + lane];

            float kr1 = k1 * c - k2 * sn;
            float kr2 = k1 * sn + k2 * c;
            float d = q1 * kr1 + q2 * kr2;
            #pragma unroll
            for (int off = 32; off; off >>= 1) d += __shfl_xor(d, off);
            d *= 0.08838834764831845f;              // 1/sqrt(128)
            float mn = fmaxf(m, d);
            float corr = __expf(m - mn);            // exp(-inf)=0 on first iter
            float e = __expf(d - mn);
            l = l * corr + e;
            a1 = a1 * corr + e * v1;
            a2 = a2 * corr + e * v2;
            m = mn;
            if (!more) break;
            s = s2; k1 = nk1; k2 = nk2; v1 = nv1; v2 = nv2; c = nc; sn = nsn;
        }
    }

    __shared__ float sm[4], sl[4], sa[4][128];
    if (lane == 0) { sm[wave] = m; sl[wave] = l; }
    sa[wave][lane] = a1;
    sa[wave][64 + lane] = a2;
    __syncthreads();

    if (wave == 0) {
        float M = fmaxf(fmaxf(sm[0], sm[1]), fmaxf(sm[2], sm[3]));
        float L = 0.f, o1 = 0.f, o2 = 0.f;
        #pragma unroll
        for (int w = 0; w < 4; ++w) {
            float ew = __expf(sm[w] - M);           // zero-token wave: sm=-inf -> ew=0
            L += sl[w] * ew;
            o1 += sa[w][lane] * ew;
            o2 += sa[w][64 + lane] * ew;
        }
        attn_out[qbase + lane]      = o1 / L;
        attn_out[qbase + 64 + lane] = o2 / L;
    }
}

// ---------------------------------------------------------------------------
extern "C" void kernel_launch(void* const* d_in, const int* in_sizes, int n_in,
                              void* d_out, int out_size, void* d_ws, size_t ws_size,
                              hipStream_t stream) {
    const int*   input_ids    = (const int*)d_in[0];
    const int*   positions    = (const int*)d_in[1];
    const float* kv_cache     = (const float*)d_in[2];
    const int*   block_tables = (const int*)d_in[3];
    const int*   context_lens = (const int*)d_in[4];
    const float* embed_tokens = (const float*)d_in[5];
    const float* embed_pos    = (const float*)d_in[6];
    const float* Wq  = (const float*)d_in[7];
    const float* Wo  = (const float*)d_in[8];
    const float* Wprm= (const float*)d_in[9];
    const float* W1  = (const float*)d_in[10];
    const float* W2  = (const float*)d_in[11];
    float* out = (float*)d_out;

    char* ws = (char*)d_ws;
    size_t off = 0;
    float* ct   = (float*)(ws + off); off += (size_t)KV_LEN * 64 * 4;     // 512 KB
    float* st   = (float*)(ws + off); off += (size_t)KV_LEN * 64 * 4;     // 512 KB
    float* emb  = (float*)(ws + off); off += (size_t)BATCH * HID * 4;     // 256 KB
    float* qbuf = (float*)(ws + off); off += (size_t)BATCH * HID * 4;
    float* attn = (float*)(ws + off); off += (size_t)BATCH * HID * 4;
    float* ao   = (float*)(ws + off); off += (size_t)BATCH * HID * 4;
    float* prm  = (float*)(ws + off); off += (size_t)BATCH * HID * 4;
    float* h1   = (float*)(ws + off); off += (size_t)BATCH * FFN * 4;     // 1 MB
    float* P    = (float*)(ws + off); off += (size_t)64 * BATCH * HID * 4; // 16 MB max partials
    (void)ws_size; (void)in_sizes; (void)n_in; (void)out_size;

    // 1. RoPE table
    rope_table_kernel<<<KV_LEN, 64, 0, stream>>>(ct, st);
    // 2. embeddings
    emb_kernel<<<BATCH, 256, 0, stream>>>(input_ids, positions, embed_tokens, embed_pos, emb);
    // 3. q = emb @ Wq  (split-K 32 chunks) -> RoPE
    gemm_partial<64><<<dim3(4, 32), 256, 0, stream>>>(emb, Wq, P, HID, HID);
    reduce_rope_q_kernel<<<128, 256, 0, stream>>>(P, 32, positions, ct, st, qbuf);
    // 4. paged attention
    attn_kernel<<<BATCH * HEADS, 256, 0, stream>>>(qbuf, kv_cache, block_tables,
                                                   context_lens, ct, st, attn);
    // 5. ao = attn @ Wo
    gemm_partial<64><<<dim3(4, 32), 256, 0, stream>>>(attn, Wo, P, HID, HID);
    reduce_kernel<<<BATCH * HID / 256, 256, 0, stream>>>(P, 32, BATCH * HID, ao, nullptr);
    // 6. prm = ao @ Wprm
    gemm_partial<64><<<dim3(4, 32), 256, 0, stream>>>(ao, Wprm, P, HID, HID);
    reduce_kernel<<<BATCH * HID / 256, 256, 0, stream>>>(P, 32, BATCH * HID, prm, nullptr);
    // 7. h1 = ao @ W1   [32, 8192]
    gemm_partial<128><<<dim3(16, 16), 256, 0, stream>>>(ao, W1, P, HID, FFN);
    reduce_kernel<<<BATCH * FFN / 256, 256, 0, stream>>>(P, 16, BATCH * FFN, h1, nullptr);
    // 8. out = h1 @ W2 + prm
    gemm_partial<128><<<dim3(4, 64), 256, 0, stream>>>(h1, W2, P, FFN, HID);
    reduce_kernel<<<BATCH * HID / 256, 256, 0, stream>>>(P, 64, BATCH * HID, out, prm);
}

// Round 2
// 480.870 us; speedup vs baseline: 1.4573x; 1.4573x over previous
//
#include <hip/hip_runtime.h>
#include <hip/hip_bf16.h>
#include <math.h>

// Problem constants (from reference)
#define BATCH   32
#define NBLK    128
#define BLOCK_T 16
#define HEADS   16
#define DHEAD   128
#define HID     2048
#define FFN     8192
#define KV_LEN  2048

#define NSPLIT  8
#define SPLIT_TOKENS (KV_LEN / NSPLIT)   // 256

// ---------------------------------------------------------------------------
// RoPE cos/sin table: [KV_LEN][64]  (freq index i = lane, covers both halves)
// ---------------------------------------------------------------------------
__global__ void rope_table_kernel(float* __restrict__ ct, float* __restrict__ st) {
    int s = blockIdx.x;          // 0..2047
    int i = threadIdx.x;         // 0..63
    float inv = powf(10000.0f, -(float)i / 64.0f);
    float ang = (float)s * inv;
    ct[s * 64 + i] = cosf(ang);
    st[s * 64 + i] = sinf(ang);
}

// ---------------------------------------------------------------------------
// emb[b][c] = embed_tokens[ids[b]][c] + embed_positions[pos[b]][c]
// ---------------------------------------------------------------------------
__global__ void emb_kernel(const int* __restrict__ ids, const int* __restrict__ pos,
                           const float* __restrict__ et, const float* __restrict__ ep,
                           float* __restrict__ emb) {
    int b = blockIdx.x;
    int id = ids[b], p = pos[b];
    const float4* a = (const float4*)(et + (size_t)id * HID);
    const float4* d = (const float4*)(ep + (size_t)p * HID);
    float4* o = (float4*)(emb + (size_t)b * HID);
    for (int c = threadIdx.x; c < HID / 4; c += 256) {
        float4 x = a[c], y = d[c];
        o[c] = make_float4(x.x + y.x, x.y + y.y, x.z + y.z, x.w + y.w);
    }
}

// ---------------------------------------------------------------------------
// Split-K skinny GEMM: X[32][K] @ W[K][N] -> P[K/BK][32][N] (partials)
// ---------------------------------------------------------------------------
template <int BK>
__global__ __launch_bounds__(256) void gemm_partial(
    const float* __restrict__ X, const float* __restrict__ W,
    float* __restrict__ P, int K, int N) {
    __shared__ float xs[BK][36];
    const int tid = threadIdx.x;
    const int k0  = blockIdx.y * BK;
    const int j   = blockIdx.x * 512 + tid * 2;

    #pragma unroll
    for (int t = tid; t < 32 * BK; t += 256) {
        int bb = t / BK, ii = t % BK;
        xs[ii][bb] = X[bb * K + k0 + ii];
    }
    __syncthreads();

    float acc[32][2];
    #pragma unroll
    for (int bb = 0; bb < 32; ++bb) { acc[bb][0] = 0.f; acc[bb][1] = 0.f; }

    const float* wp = W + (size_t)k0 * N + j;
    for (int ii = 0; ii < BK; ++ii) {
        const float2 w = *reinterpret_cast<const float2*>(wp + (size_t)ii * N);
        #pragma unroll
        for (int g = 0; g < 8; ++g) {
            const float4 xv = *reinterpret_cast<const float4*>(&xs[ii][g * 4]);
            acc[4 * g + 0][0] += xv.x * w.x; acc[4 * g + 0][1] += xv.x * w.y;
            acc[4 * g + 1][0] += xv.y * w.x; acc[4 * g + 1][1] += xv.y * w.y;
            acc[4 * g + 2][0] += xv.z * w.x; acc[4 * g + 2][1] += xv.z * w.y;
            acc[4 * g + 3][0] += xv.w * w.x; acc[4 * g + 3][1] += xv.w * w.y;
        }
    }

    float* pp = P + ((size_t)blockIdx.y * 32) * N + j;
    #pragma unroll
    for (int bb = 0; bb < 32; ++bb) {
        *reinterpret_cast<float2*>(pp + (size_t)bb * N) = make_float2(acc[bb][0], acc[bb][1]);
    }
}

// ---------------------------------------------------------------------------
// Reduce split-K partials: out[idx] = sum_c P[c][idx] (+ addsrc[idx])
// ---------------------------------------------------------------------------
__global__ void reduce_kernel(const float* __restrict__ P, int nch, int total,
                              float* __restrict__ out, const float* __restrict__ addsrc) {
    int idx = blockIdx.x * 256 + threadIdx.x;
    if (idx >= total) return;
    float s = 0.f;
    for (int c = 0; c < nch; ++c) s += P[(size_t)c * total + idx];
    if (addsrc) s += addsrc[idx];
    out[idx] = s;
}

// ---------------------------------------------------------------------------
// Reduce Wq partials + apply RoPE at positions[b] -> q[32][2048]
// ---------------------------------------------------------------------------
__global__ void reduce_rope_q_kernel(const float* __restrict__ P, int nch,
                                     const int* __restrict__ positions,
                                     const float* __restrict__ ct, const float* __restrict__ st,
                                     float* __restrict__ qout) {
    int idx = blockIdx.x * 256 + threadIdx.x;   // 32*16*64 = 32768 threads
    int i = idx & 63, hh = (idx >> 6) & 15, b = idx >> 10;
    int base = b * HID + hh * DHEAD;
    float q1 = 0.f, q2 = 0.f;
    for (int c = 0; c < nch; ++c) {
        q1 += P[(size_t)c * (BATCH * HID) + base + i];
        q2 += P[(size_t)c * (BATCH * HID) + base + 64 + i];
    }
    int pos = positions[b];
    float co = ct[pos * 64 + i], si = st[pos * 64 + i];
    qout[base + i]      = q1 * co - q2 * si;
    qout[base + 64 + i] = q1 * si + q2 * co;
}

// ---------------------------------------------------------------------------
// Flash-decode paged attention, stage 1: partials per (b, h, split).
// Block handles one (b,h,split); 4 waves stride tokens by 4 within the split.
// lane i holds dims {i, i+64} (RoPE pair is lane-local). Online softmax per
// wave, LDS combine, write (m, l, acc[128]) to workspace.
// Grid = B*H*NSPLIT = 4096 blocks -> 32 resident waves/CU -> latency hidden.
// ---------------------------------------------------------------------------
__global__ __launch_bounds__(256) void attn_partial_kernel(
    const float* __restrict__ q, const float* __restrict__ kv,
    const int* __restrict__ block_tables, const int* __restrict__ context_lens,
    const float* __restrict__ ct, const float* __restrict__ st,
    float* __restrict__ pm, float* __restrict__ pl, float* __restrict__ pacc) {
    const int idx = blockIdx.x;
    const int split = idx & (NSPLIT - 1);
    const int h = (idx >> 3) & 15;
    const int b = idx >> 7;
    const int wave = threadIdx.x >> 6, lane = threadIdx.x & 63;

    const int ctx = context_lens[b];
    const int s_begin = split * SPLIT_TOKENS;
    const int s_end = min(s_begin + SPLIT_TOKENS, ctx);

    const int qbase = b * HID + h * DHEAD;
    const float q1 = q[qbase + lane], q2 = q[qbase + 64 + lane];

    float m = -INFINITY, l = 0.f, a1 = 0.f, a2 = 0.f;

    auto kbase = [&](int s) -> const float* {
        int blk = block_tables[b * NBLK + (s >> 4)];
        return kv + (size_t)blk * 65536 + (size_t)(s & 15) * 2048 + h * DHEAD;
    };

    int s = s_begin + wave;
    if (s < s_end) {
        const float* kp = kbase(s);
        float k1 = kp[lane], k2 = kp[64 + lane];
        float v1 = kp[32768 + lane], v2 = kp[32768 + 64 + lane];
        float c = ct[s * 64 + lane], sn = st[s * 64 + lane];
        for (;;) {
            int s2 = s + 4;
            bool more = s2 < s_end;
            int sp = more ? s2 : s;                 // safe re-read when done
            const float* kp2 = kbase(sp);
            float nk1 = kp2[lane], nk2 = kp2[64 + lane];
            float nv1 = kp2[32768 + lane], nv2 = kp2[32768 + 64 + lane];
            float nc = ct[sp * 64 + lane], nsn = st[sp * 64 + lane];

            float kr1 = k1 * c - k2 * sn;
            float kr2 = k1 * sn + k2 * c;
            float d = q1 * kr1 + q2 * kr2;
            #pragma unroll
            for (int off = 32; off; off >>= 1) d += __shfl_xor(d, off);
            d *= 0.08838834764831845f;              // 1/sqrt(128)
            float mn = fmaxf(m, d);
            float corr = __expf(m - mn);
            float e = __expf(d - mn);
            l = l * corr + e;
            a1 = a1 * corr + e * v1;
            a2 = a2 * corr + e * v2;
            m = mn;
            if (!more) break;
            s = s2; k1 = nk1; k2 = nk2; v1 = nv1; v2 = nv2; c = nc; sn = nsn;
        }
    }

    __shared__ float sm[4], sl[4], sa[4][128];
    if (lane == 0) { sm[wave] = m; sl[wave] = l; }
    sa[wave][lane] = a1;
    sa[wave][64 + lane] = a2;
    __syncthreads();

    if (wave == 0) {
        float M = fmaxf(fmaxf(sm[0], sm[1]), fmaxf(sm[2], sm[3]));
        float L = 0.f, o1 = 0.f, o2 = 0.f;
        #pragma unroll
        for (int w = 0; w < 4; ++w) {
            // guard: empty wave (sm=-inf) with M=-inf would give exp(nan)
            float ew = (sm[w] == -INFINITY) ? 0.f : __expf(sm[w] - M);
            L += sl[w] * ew;
            o1 += sa[w][lane] * ew;
            o2 += sa[w][64 + lane] * ew;
        }
        if (lane == 0) { pm[idx] = M; pl[idx] = L; }
        pacc[(size_t)idx * 128 + lane]      = o1;
        pacc[(size_t)idx * 128 + 64 + lane] = o2;
    }
}

// ---------------------------------------------------------------------------
// Flash-decode stage 2: combine NSPLIT partials per (b,h).
// ---------------------------------------------------------------------------
__global__ void attn_combine_kernel(const float* __restrict__ pm, const float* __restrict__ pl,
                                    const float* __restrict__ pacc, float* __restrict__ attn_out) {
    const int bh = blockIdx.x;         // b*16 + h
    const int lane = threadIdx.x;      // 64
    const int base = bh * NSPLIT;
    float M = -INFINITY;
    #pragma unroll
    for (int sp = 0; sp < NSPLIT; ++sp) M = fmaxf(M, pm[base + sp]);
    float L = 0.f, o1 = 0.f, o2 = 0.f;
    #pragma unroll
    for (int sp = 0; sp < NSPLIT; ++sp) {
        float mv = pm[base + sp];
        float ew = (mv == -INFINITY) ? 0.f : __expf(mv - M);
        L  += pl[base + sp] * ew;
        o1 += pacc[(size_t)(base + sp) * 128 + lane] * ew;
        o2 += pacc[(size_t)(base + sp) * 128 + 64 + lane] * ew;
    }
    attn_out[bh * 128 + lane]      = o1 / L;
    attn_out[bh * 128 + 64 + lane] = o2 / L;
}

// ---------------------------------------------------------------------------
extern "C" void kernel_launch(void* const* d_in, const int* in_sizes, int n_in,
                              void* d_out, int out_size, void* d_ws, size_t ws_size,
                              hipStream_t stream) {
    const int*   input_ids    = (const int*)d_in[0];
    const int*   positions    = (const int*)d_in[1];
    const float* kv_cache     = (const float*)d_in[2];
    const int*   block_tables = (const int*)d_in[3];
    const int*   context_lens = (const int*)d_in[4];
    const float* embed_tokens = (const float*)d_in[5];
    const float* embed_pos    = (const float*)d_in[6];
    const float* Wq  = (const float*)d_in[7];
    const float* Wo  = (const float*)d_in[8];
    const float* Wprm= (const float*)d_in[9];
    const float* W1  = (const float*)d_in[10];
    const float* W2  = (const float*)d_in[11];
    float* out = (float*)d_out;

    char* ws = (char*)d_ws;
    size_t off = 0;
    float* ct   = (float*)(ws + off); off += (size_t)KV_LEN * 64 * 4;     // 512 KB
    float* st   = (float*)(ws + off); off += (size_t)KV_LEN * 64 * 4;     // 512 KB
    float* emb  = (float*)(ws + off); off += (size_t)BATCH * HID * 4;     // 256 KB
    float* qbuf = (float*)(ws + off); off += (size_t)BATCH * HID * 4;
    float* attn = (float*)(ws + off); off += (size_t)BATCH * HID * 4;
    float* ao   = (float*)(ws + off); off += (size_t)BATCH * HID * 4;
    float* prm  = (float*)(ws + off); off += (size_t)BATCH * HID * 4;
    float* h1   = (float*)(ws + off); off += (size_t)BATCH * FFN * 4;     // 1 MB
    float* pm   = (float*)(ws + off); off += (size_t)BATCH * HEADS * NSPLIT * 4;
    float* plv  = (float*)(ws + off); off += (size_t)BATCH * HEADS * NSPLIT * 4;
    float* pacc = (float*)(ws + off); off += (size_t)BATCH * HEADS * NSPLIT * 128 * 4; // 2 MB
    float* P    = (float*)(ws + off); off += (size_t)64 * BATCH * HID * 4; // 16 MB max partials
    (void)ws_size; (void)in_sizes; (void)n_in; (void)out_size;

    // 1. RoPE table
    rope_table_kernel<<<KV_LEN, 64, 0, stream>>>(ct, st);
    // 2. embeddings
    emb_kernel<<<BATCH, 256, 0, stream>>>(input_ids, positions, embed_tokens, embed_pos, emb);
    // 3. q = emb @ Wq  (split-K 32 chunks) -> RoPE
    gemm_partial<64><<<dim3(4, 32), 256, 0, stream>>>(emb, Wq, P, HID, HID);
    reduce_rope_q_kernel<<<128, 256, 0, stream>>>(P, 32, positions, ct, st, qbuf);
    // 4. paged attention (flash-decode: 8 token-splits + combine)
    attn_partial_kernel<<<BATCH * HEADS * NSPLIT, 256, 0, stream>>>(
        qbuf, kv_cache, block_tables, context_lens, ct, st, pm, plv, pacc);
    attn_combine_kernel<<<BATCH * HEADS, 64, 0, stream>>>(pm, plv, pacc, attn);
    // 5. ao = attn @ Wo
    gemm_partial<64><<<dim3(4, 32), 256, 0, stream>>>(attn, Wo, P, HID, HID);
    reduce_kernel<<<BATCH * HID / 256, 256, 0, stream>>>(P, 32, BATCH * HID, ao, nullptr);
    // 6. prm = ao @ Wprm
    gemm_partial<64><<<dim3(4, 32), 256, 0, stream>>>(ao, Wprm, P, HID, HID);
    reduce_kernel<<<BATCH * HID / 256, 256, 0, stream>>>(P, 32, BATCH * HID, prm, nullptr);
    // 7. h1 = ao @ W1   [32, 8192]
    gemm_partial<128><<<dim3(16, 16), 256, 0, stream>>>(ao, W1, P, HID, FFN);
    reduce_kernel<<<BATCH * FFN / 256, 256, 0, stream>>>(P, 16, BATCH * FFN, h1, nullptr);
    // 8. out = h1 @ W2 + prm
    gemm_partial<128><<<dim3(4, 64), 256, 0, stream>>>(h1, W2, P, FFN, HID);
    reduce_kernel<<<BATCH * HID / 256, 256, 0, stream>>>(P, 64, BATCH * HID, out, prm);
}

// Round 3
// 470.934 us; speedup vs baseline: 1.4880x; 1.0211x over previous
//
#include <hip/hip_runtime.h>
#include <hip/hip_bf16.h>
#include <math.h>

// Problem constants (from reference)
#define BATCH   32
#define NBLK    128
#define BLOCK_T 16
#define HEADS   16
#define DHEAD   128
#define HID     2048
#define FFN     8192
#define KV_LEN  2048

#define NSPLIT  16
#define SPLIT_TOKENS (KV_LEN / NSPLIT)   // 128

// ---------------------------------------------------------------------------
// prep: fused RoPE cos/sin table (float2 interleaved) + embeddings
// grid = 512 + 32 blocks, 256 threads
// ---------------------------------------------------------------------------
__global__ void prep_kernel(const int* __restrict__ ids, const int* __restrict__ pos,
                            const float* __restrict__ et, const float* __restrict__ ep,
                            float2* __restrict__ cs, float* __restrict__ emb) {
    if (blockIdx.x < 512) {
        int s = blockIdx.x * 4 + (threadIdx.x >> 6);   // 0..2047
        int i = threadIdx.x & 63;
        float inv = powf(10000.0f, -(float)i / 64.0f);
        float ang = (float)s * inv;
        cs[s * 64 + i] = make_float2(cosf(ang), sinf(ang));
    } else {
        int b = blockIdx.x - 512;
        int id = ids[b], p = pos[b];
        const float4* a = (const float4*)(et + (size_t)id * HID);
        const float4* d = (const float4*)(ep + (size_t)p * HID);
        float4* o = (float4*)(emb + (size_t)b * HID);
        for (int c = threadIdx.x; c < HID / 4; c += 256) {
            float4 x = a[c], y = d[c];
            o[c] = make_float4(x.x + y.x, x.y + y.y, x.z + y.z, x.w + y.w);
        }
    }
}

// ---------------------------------------------------------------------------
// Split-K skinny GEMM: X[32][K] @ W[K][N] -> P[K/BK][32][N] (partials)
// ---------------------------------------------------------------------------
template <int BK>
__global__ __launch_bounds__(256) void gemm_partial(
    const float* __restrict__ X, const float* __restrict__ W,
    float* __restrict__ P, int K, int N) {
    __shared__ float xs[BK][36];
    const int tid = threadIdx.x;
    const int k0  = blockIdx.y * BK;
    const int j   = blockIdx.x * 512 + tid * 2;

    #pragma unroll
    for (int t = tid; t < 32 * BK; t += 256) {
        int bb = t / BK, ii = t % BK;
        xs[ii][bb] = X[bb * K + k0 + ii];
    }
    __syncthreads();

    float acc[32][2];
    #pragma unroll
    for (int bb = 0; bb < 32; ++bb) { acc[bb][0] = 0.f; acc[bb][1] = 0.f; }

    const float* wp = W + (size_t)k0 * N + j;
    float2 w = *reinterpret_cast<const float2*>(wp);
    for (int ii = 0; ii < BK; ++ii) {
        // clamped prefetch of next row (always safe, issued early)
        const int nxt = (ii + 1 < BK) ? ii + 1 : ii;
        const float2 wn = *reinterpret_cast<const float2*>(wp + (size_t)nxt * N);
        #pragma unroll
        for (int g = 0; g < 8; ++g) {
            const float4 xv = *reinterpret_cast<const float4*>(&xs[ii][g * 4]);
            acc[4 * g + 0][0] += xv.x * w.x; acc[4 * g + 0][1] += xv.x * w.y;
            acc[4 * g + 1][0] += xv.y * w.x; acc[4 * g + 1][1] += xv.y * w.y;
            acc[4 * g + 2][0] += xv.z * w.x; acc[4 * g + 2][1] += xv.z * w.y;
            acc[4 * g + 3][0] += xv.w * w.x; acc[4 * g + 3][1] += xv.w * w.y;
        }
        w = wn;
    }

    float* pp = P + ((size_t)blockIdx.y * 32) * N + j;
    #pragma unroll
    for (int bb = 0; bb < 32; ++bb) {
        *reinterpret_cast<float2*>(pp + (size_t)bb * N) = make_float2(acc[bb][0], acc[bb][1]);
    }
}

// ---------------------------------------------------------------------------
// Reduce split-K partials: out[idx] = sum_c P[c][idx] (+ addsrc[idx])
// ---------------------------------------------------------------------------
__global__ void reduce_kernel(const float* __restrict__ P, int nch, int total,
                              float* __restrict__ out, const float* __restrict__ addsrc) {
    int idx = blockIdx.x * 256 + threadIdx.x;
    if (idx >= total) return;
    float s = 0.f;
    for (int c = 0; c < nch; ++c) s += P[(size_t)c * total + idx];
    if (addsrc) s += addsrc[idx];
    out[idx] = s;
}

// ---------------------------------------------------------------------------
// Reduce Wq partials + apply RoPE at positions[b] -> q[32][2048]
// ---------------------------------------------------------------------------
__global__ void reduce_rope_q_kernel(const float* __restrict__ P, int nch,
                                     const int* __restrict__ positions,
                                     const float2* __restrict__ cs,
                                     float* __restrict__ qout) {
    int idx = blockIdx.x * 256 + threadIdx.x;   // 32*16*64 = 32768 threads
    int i = idx & 63, hh = (idx >> 6) & 15, b = idx >> 10;
    int base = b * HID + hh * DHEAD;
    float q1 = 0.f, q2 = 0.f;
    for (int c = 0; c < nch; ++c) {
        q1 += P[(size_t)c * (BATCH * HID) + base + i];
        q2 += P[(size_t)c * (BATCH * HID) + base + 64 + i];
    }
    int pos = positions[b];
    float2 c2 = cs[pos * 64 + i];
    qout[base + i]      = q1 * c2.x - q2 * c2.y;
    qout[base + 64 + i] = q1 * c2.y + q2 * c2.x;
}

// ---------------------------------------------------------------------------
// Flash-decode paged attention, stage 1: partials per (b, h, split).
// Block = one (b,h,split); 4 waves; wave w owns tokens {8g+2w, 8g+2w+1}.
// Block-table hoisted to LDS; 4-token software pipeline (named slots A..D);
// clamped loads + masked softmax for uniform loop count.
// lane i holds dims {i, i+64} (RoPE pair lane-local). Online softmax.
// ---------------------------------------------------------------------------
__global__ __launch_bounds__(256) void attn_partial_kernel(
    const float* __restrict__ q, const float* __restrict__ kv,
    const int* __restrict__ block_tables, const int* __restrict__ context_lens,
    const float2* __restrict__ cs,
    float* __restrict__ pm, float* __restrict__ pl, float* __restrict__ pacc) {
    const int idx = blockIdx.x;
    const int split = idx & (NSPLIT - 1);
    const int h = (idx >> 4) & 15;
    const int b = idx >> 8;
    const int wave = threadIdx.x >> 6, lane = threadIdx.x & 63;

    const int ctx = context_lens[b];
    const int s_begin = split * SPLIT_TOKENS;
    const int len = min(SPLIT_TOKENS, ctx - s_begin);   // may be <= 0

    __shared__ int bt[SPLIT_TOKENS / 16];               // 8 entries
    __shared__ float sm[4], sl[4], sa[4][128];
    if (threadIdx.x < SPLIT_TOKENS / 16)
        bt[threadIdx.x] = block_tables[b * NBLK + (s_begin >> 4) + threadIdx.x];
    __syncthreads();

    const int qbase = b * HID + h * DHEAD;
    const float q1 = q[qbase + lane], q2 = q[qbase + 64 + lane];

    float m = -INFINITY, l = 0.f, a1 = 0.f, a2 = 0.f;

    if (len > 0) {
        const int t0 = 2 * wave;
        const int ng = (len + 7) >> 3;                  // groups of 8 tokens
        const int NI = 2 * ((ng + 1) & ~1);             // tokens/wave, multiple of 4

        // token index for this wave, i-th in sequence
        #define TOK(i) (8 * ((i) >> 1) + t0 + ((i) & 1))

        #define LOADTOK(t, K1, K2, V1, V2, CS) {                                   \
            int tc = min((t), len - 1);                                            \
            const float* kp = kv + (size_t)bt[tc >> 4] * 65536                     \
                                 + (size_t)(tc & 15) * 2048 + h * DHEAD;           \
            K1 = kp[lane];          K2 = kp[64 + lane];                            \
            V1 = kp[32768 + lane];  V2 = kp[32768 + 64 + lane];                    \
            CS = cs[(size_t)(s_begin + tc) * 64 + lane];                           \
        }

        #define PROC(t, K1, K2, V1, V2, CS) {                                      \
            float kr1 = K1 * CS.x - K2 * CS.y;                                     \
            float kr2 = K1 * CS.y + K2 * CS.x;                                     \
            float d = q1 * kr1 + q2 * kr2;                                         \
            d += __shfl_xor(d, 32); d += __shfl_xor(d, 16);                        \
            d += __shfl_xor(d, 8);  d += __shfl_xor(d, 4);                         \
            d += __shfl_xor(d, 2);  d += __shfl_xor(d, 1);                         \
            d = ((t) < len) ? d * 0.08838834764831845f : -INFINITY;                \
            float mn = fmaxf(m, d);                                                \
            float ms = fmaxf(mn, -3.0e38f);                                        \
            float corr = __expf(m - ms);                                           \
            float e = __expf(d - ms);                                              \
            l = l * corr + e;                                                      \
            a1 = a1 * corr + e * V1;                                               \
            a2 = a2 * corr + e * V2;                                               \
            m = mn;                                                                \
        }

        float k1A, k2A, v1A, v2A; float2 csA;
        float k1B, k2B, v1B, v2B; float2 csB;
        float k1C, k2C, v1C, v2C; float2 csC;
        float k1D, k2D, v1D, v2D; float2 csD;

        LOADTOK(TOK(0), k1A, k2A, v1A, v2A, csA);
        LOADTOK(TOK(1), k1B, k2B, v1B, v2B, csB);
        LOADTOK(TOK(2), k1C, k2C, v1C, v2C, csC);
        LOADTOK(TOK(3), k1D, k2D, v1D, v2D, csD);

        for (int i = 0; i < NI; i += 4) {
            PROC(TOK(i + 0), k1A, k2A, v1A, v2A, csA);
            LOADTOK(TOK(i + 4), k1A, k2A, v1A, v2A, csA);
            PROC(TOK(i + 1), k1B, k2B, v1B, v2B, csB);
            LOADTOK(TOK(i + 5), k1B, k2B, v1B, v2B, csB);
            PROC(TOK(i + 2), k1C, k2C, v1C, v2C, csC);
            LOADTOK(TOK(i + 6), k1C, k2C, v1C, v2C, csC);
            PROC(TOK(i + 3), k1D, k2D, v1D, v2D, csD);
            LOADTOK(TOK(i + 7), k1D, k2D, v1D, v2D, csD);
        }
        #undef TOK
        #undef LOADTOK
        #undef PROC
    }

    if (lane == 0) { sm[wave] = m; sl[wave] = l; }
    sa[wave][lane] = a1;
    sa[wave][64 + lane] = a2;
    __syncthreads();

    if (wave == 0) {
        float M = fmaxf(fmaxf(sm[0], sm[1]), fmaxf(sm[2], sm[3]));
        float L = 0.f, o1 = 0.f, o2 = 0.f;
        #pragma unroll
        for (int w = 0; w < 4; ++w) {
            float ew = (sm[w] == -INFINITY) ? 0.f : __expf(sm[w] - M);
            L += sl[w] * ew;
            o1 += sa[w][lane] * ew;
            o2 += sa[w][64 + lane] * ew;
        }
        if (lane == 0) { pm[idx] = M; pl[idx] = L; }
        pacc[(size_t)idx * 128 + lane]      = o1;
        pacc[(size_t)idx * 128 + 64 + lane] = o2;
    }
}

// ---------------------------------------------------------------------------
// Flash-decode stage 2: combine NSPLIT partials per (b,h).
// ---------------------------------------------------------------------------
__global__ void attn_combine_kernel(const float* __restrict__ pm, const float* __restrict__ pl,
                                    const float* __restrict__ pacc, float* __restrict__ attn_out) {
    const int bh = blockIdx.x;         // b*16 + h
    const int lane = threadIdx.x;      // 64
    const int base = bh * NSPLIT;
    float M = -INFINITY;
    #pragma unroll
    for (int sp = 0; sp < NSPLIT; ++sp) M = fmaxf(M, pm[base + sp]);
    float L = 0.f, o1 = 0.f, o2 = 0.f;
    #pragma unroll
    for (int sp = 0; sp < NSPLIT; ++sp) {
        float mv = pm[base + sp];
        float ew = (mv == -INFINITY) ? 0.f : __expf(mv - M);
        L  += pl[base + sp] * ew;
        o1 += pacc[(size_t)(base + sp) * 128 + lane] * ew;
        o2 += pacc[(size_t)(base + sp) * 128 + 64 + lane] * ew;
    }
    attn_out[bh * 128 + lane]      = o1 / L;
    attn_out[bh * 128 + 64 + lane] = o2 / L;
}

// ---------------------------------------------------------------------------
extern "C" void kernel_launch(void* const* d_in, const int* in_sizes, int n_in,
                              void* d_out, int out_size, void* d_ws, size_t ws_size,
                              hipStream_t stream) {
    const int*   input_ids    = (const int*)d_in[0];
    const int*   positions    = (const int*)d_in[1];
    const float* kv_cache     = (const float*)d_in[2];
    const int*   block_tables = (const int*)d_in[3];
    const int*   context_lens = (const int*)d_in[4];
    const float* embed_tokens = (const float*)d_in[5];
    const float* embed_pos    = (const float*)d_in[6];
    const float* Wq  = (const float*)d_in[7];
    const float* Wo  = (const float*)d_in[8];
    const float* Wprm= (const float*)d_in[9];
    const float* W1  = (const float*)d_in[10];
    const float* W2  = (const float*)d_in[11];
    float* out = (float*)d_out;

    char* ws = (char*)d_ws;
    size_t off = 0;
    float2* cs  = (float2*)(ws + off); off += (size_t)KV_LEN * 64 * 8;    // 1 MB
    float* emb  = (float*)(ws + off); off += (size_t)BATCH * HID * 4;     // 256 KB
    float* qbuf = (float*)(ws + off); off += (size_t)BATCH * HID * 4;
    float* attn = (float*)(ws + off); off += (size_t)BATCH * HID * 4;
    float* ao   = (float*)(ws + off); off += (size_t)BATCH * HID * 4;
    float* prm  = (float*)(ws + off); off += (size_t)BATCH * HID * 4;
    float* h1   = (float*)(ws + off); off += (size_t)BATCH * FFN * 4;     // 1 MB
    float* pm   = (float*)(ws + off); off += (size_t)BATCH * HEADS * NSPLIT * 4;
    float* plv  = (float*)(ws + off); off += (size_t)BATCH * HEADS * NSPLIT * 4;
    float* pacc = (float*)(ws + off); off += (size_t)BATCH * HEADS * NSPLIT * 128 * 4; // 4 MB
    float* P    = (float*)(ws + off); off += (size_t)64 * BATCH * HID * 4; // 16 MB max partials
    (void)ws_size; (void)in_sizes; (void)n_in; (void)out_size;

    // 1. RoPE cos/sin table + embeddings (fused)
    prep_kernel<<<544, 256, 0, stream>>>(input_ids, positions, embed_tokens, embed_pos, cs, emb);
    // 2. q = emb @ Wq  (split-K 32 chunks) -> RoPE
    gemm_partial<64><<<dim3(4, 32), 256, 0, stream>>>(emb, Wq, P, HID, HID);
    reduce_rope_q_kernel<<<128, 256, 0, stream>>>(P, 32, positions, cs, qbuf);
    // 3. paged attention (flash-decode: 16 token-splits + combine)
    attn_partial_kernel<<<BATCH * HEADS * NSPLIT, 256, 0, stream>>>(
        qbuf, kv_cache, block_tables, context_lens, cs, pm, plv, pacc);
    attn_combine_kernel<<<BATCH * HEADS, 64, 0, stream>>>(pm, plv, pacc, attn);
    // 4. ao = attn @ Wo
    gemm_partial<64><<<dim3(4, 32), 256, 0, stream>>>(attn, Wo, P, HID, HID);
    reduce_kernel<<<BATCH * HID / 256, 256, 0, stream>>>(P, 32, BATCH * HID, ao, nullptr);
    // 5. prm = ao @ Wprm
    gemm_partial<64><<<dim3(4, 32), 256, 0, stream>>>(ao, Wprm, P, HID, HID);
    reduce_kernel<<<BATCH * HID / 256, 256, 0, stream>>>(P, 32, BATCH * HID, prm, nullptr);
    // 6. h1 = ao @ W1   [32, 8192]
    gemm_partial<128><<<dim3(16, 16), 256, 0, stream>>>(ao, W1, P, HID, FFN);
    reduce_kernel<<<BATCH * FFN / 256, 256, 0, stream>>>(P, 16, BATCH * FFN, h1, nullptr);
    // 7. out = h1 @ W2 + prm
    gemm_partial<128><<<dim3(4, 64), 256, 0, stream>>>(h1, W2, P, FFN, HID);
    reduce_kernel<<<BATCH * HID / 256, 256, 0, stream>>>(P, 64, BATCH * HID, out, prm);
}

// Round 4
// 366.137 us; speedup vs baseline: 1.9139x; 1.2862x over previous
//
#include <hip/hip_runtime.h>
#include <hip/hip_bf16.h>
#include <math.h>

// Problem constants (from reference)
#define BATCH   32
#define NBLK    128
#define BLOCK_T 16
#define HEADS   16
#define DHEAD   128
#define HID     2048
#define FFN     8192
#define KV_LEN  2048

#define NSPLIT  16
#define SPLIT_TOKENS 128

// ---------------------------------------------------------------------------
// prep: RoPE cos/sin tables (scalar layout [tok][64], freq-major) + embeddings
// ---------------------------------------------------------------------------
__global__ void prep_kernel(const int* __restrict__ ids, const int* __restrict__ pos,
                            const float* __restrict__ et, const float* __restrict__ ep,
                            float* __restrict__ c4f, float* __restrict__ s4f,
                            float* __restrict__ emb) {
    if (blockIdx.x < 512) {
        int s = blockIdx.x * 4 + (threadIdx.x >> 6);   // 0..2047
        int i = threadIdx.x & 63;
        float inv = powf(10000.0f, -(float)i / 64.0f);
        float ang = (float)s * inv;
        c4f[s * 64 + i] = cosf(ang);
        s4f[s * 64 + i] = sinf(ang);
    } else {
        int b = blockIdx.x - 512;
        int id = ids[b], p = pos[b];
        const float4* a = (const float4*)(et + (size_t)id * HID);
        const float4* d = (const float4*)(ep + (size_t)p * HID);
        float4* o = (float4*)(emb + (size_t)b * HID);
        for (int c = threadIdx.x; c < HID / 4; c += 256) {
            float4 x = a[c], y = d[c];
            o[c] = make_float4(x.x + y.x, x.y + y.y, x.z + y.z, x.w + y.w);
        }
    }
}

// ---------------------------------------------------------------------------
// Split-K skinny GEMM: X[32][K] @ W[K][N] -> P[K/KC][32][N] (partials)
// Thread: 4 consecutive cols (float4 W loads), all 32 batch rows.
// Double-buffered 8-deep W prefetch -> 8 KB in flight per wave.
// grid = (N/1024, K/KC)
// ---------------------------------------------------------------------------
template <int KC>
__global__ __launch_bounds__(256) void gemm_partial(
    const float* __restrict__ X, const float* __restrict__ W,
    float* __restrict__ P, int K, int N) {
    __shared__ float xs[KC][36];          // xs[k][batch], 144B rows (16B-aligned)
    const int tid = threadIdx.x;
    const int k0  = blockIdx.y * KC;
    const int j   = blockIdx.x * 1024 + tid * 4;

    // stage X[32][k0..k0+KC) transposed
    #pragma unroll
    for (int t = tid; t < 32 * KC / 4; t += 256) {
        int bb = t / (KC / 4), qq = t % (KC / 4);
        float4 xv = *reinterpret_cast<const float4*>(X + (size_t)bb * K + k0 + 4 * qq);
        xs[4 * qq + 0][bb] = xv.x; xs[4 * qq + 1][bb] = xv.y;
        xs[4 * qq + 2][bb] = xv.z; xs[4 * qq + 3][bb] = xv.w;
    }
    __syncthreads();

    float acc[32][4];
    #pragma unroll
    for (int bb = 0; bb < 32; ++bb)
        { acc[bb][0] = 0.f; acc[bb][1] = 0.f; acc[bb][2] = 0.f; acc[bb][3] = 0.f; }

    const float* wp = W + (size_t)k0 * N + j;
    float4 bufA[8], bufB[8];
    #pragma unroll
    for (int u = 0; u < 8; ++u)
        bufA[u] = *reinterpret_cast<const float4*>(wp + (size_t)u * N);

    #define GEMM_FMA8(BUF, KK)                                                  \
        _Pragma("unroll")                                                       \
        for (int u = 0; u < 8; ++u) {                                           \
            const float4 w = BUF[u];                                            \
            _Pragma("unroll")                                                   \
            for (int g = 0; g < 8; ++g) {                                       \
                const float4 xv = *reinterpret_cast<const float4*>(&xs[(KK) + u][g * 4]); \
                acc[4*g+0][0] = fmaf(xv.x, w.x, acc[4*g+0][0]);                 \
                acc[4*g+0][1] = fmaf(xv.x, w.y, acc[4*g+0][1]);                 \
                acc[4*g+0][2] = fmaf(xv.x, w.z, acc[4*g+0][2]);                 \
                acc[4*g+0][3] = fmaf(xv.x, w.w, acc[4*g+0][3]);                 \
                acc[4*g+1][0] = fmaf(xv.y, w.x, acc[4*g+1][0]);                 \
                acc[4*g+1][1] = fmaf(xv.y, w.y, acc[4*g+1][1]);                 \
                acc[4*g+1][2] = fmaf(xv.y, w.z, acc[4*g+1][2]);                 \
                acc[4*g+1][3] = fmaf(xv.y, w.w, acc[4*g+1][3]);                 \
                acc[4*g+2][0] = fmaf(xv.z, w.x, acc[4*g+2][0]);                 \
                acc[4*g+2][1] = fmaf(xv.z, w.y, acc[4*g+2][1]);                 \
                acc[4*g+2][2] = fmaf(xv.z, w.z, acc[4*g+2][2]);                 \
                acc[4*g+2][3] = fmaf(xv.z, w.w, acc[4*g+2][3]);                 \
                acc[4*g+3][0] = fmaf(xv.w, w.x, acc[4*g+3][0]);                 \
                acc[4*g+3][1] = fmaf(xv.w, w.y, acc[4*g+3][1]);                 \
                acc[4*g+3][2] = fmaf(xv.w, w.z, acc[4*g+3][2]);                 \
                acc[4*g+3][3] = fmaf(xv.w, w.w, acc[4*g+3][3]);                 \
            }                                                                   \
        }

    for (int kk = 0; kk < KC; kk += 16) {
        // issue B loads (rows kk+8..kk+15)
        #pragma unroll
        for (int u = 0; u < 8; ++u) {
            int rr = kk + 8 + u;
            bufB[u] = *reinterpret_cast<const float4*>(wp + (size_t)rr * N);
        }
        GEMM_FMA8(bufA, kk)
        // issue A loads for next chunk (clamped; tail loads unused)
        #pragma unroll
        for (int u = 0; u < 8; ++u) {
            int rr = kk + 16 + u; rr = (rr < KC) ? rr : (KC - 1);
            bufA[u] = *reinterpret_cast<const float4*>(wp + (size_t)rr * N);
        }
        GEMM_FMA8(bufB, kk + 8)
    }
    #undef GEMM_FMA8

    float* pp = P + ((size_t)blockIdx.y * 32) * N + j;
    #pragma unroll
    for (int bb = 0; bb < 32; ++bb)
        *reinterpret_cast<float4*>(pp + (size_t)bb * N) =
            make_float4(acc[bb][0], acc[bb][1], acc[bb][2], acc[bb][3]);
}

// ---------------------------------------------------------------------------
// float4 reduce of split-K partials
// ---------------------------------------------------------------------------
__global__ void reduce4_kernel(const float* __restrict__ P, int nch, int total4,
                               float* __restrict__ out) {
    int idx4 = blockIdx.x * 256 + threadIdx.x;
    if (idx4 >= total4) return;
    const float4* P4 = (const float4*)P;
    float4 s = make_float4(0.f, 0.f, 0.f, 0.f);
    for (int c = 0; c < nch; ++c) {
        float4 v = P4[(size_t)c * total4 + idx4];
        s.x += v.x; s.y += v.y; s.z += v.z; s.w += v.w;
    }
    ((float4*)out)[idx4] = s;
}

// dual-source reduce: out = sum(P1 chunks) + sum(P2 chunks)
__global__ void reduce4_dual_kernel(const float* __restrict__ P1, int n1,
                                    const float* __restrict__ P2, int n2,
                                    int total4, float* __restrict__ out) {
    int idx4 = blockIdx.x * 256 + threadIdx.x;
    if (idx4 >= total4) return;
    const float4* A = (const float4*)P1;
    const float4* B = (const float4*)P2;
    float4 s = make_float4(0.f, 0.f, 0.f, 0.f);
    for (int c = 0; c < n1; ++c) {
        float4 v = A[(size_t)c * total4 + idx4];
        s.x += v.x; s.y += v.y; s.z += v.z; s.w += v.w;
    }
    for (int c = 0; c < n2; ++c) {
        float4 v = B[(size_t)c * total4 + idx4];
        s.x += v.x; s.y += v.y; s.z += v.z; s.w += v.w;
    }
    ((float4*)out)[idx4] = s;
}

// ---------------------------------------------------------------------------
// Reduce Wq partials + apply RoPE at positions[b] -> q[32][2048]
// ---------------------------------------------------------------------------
__global__ void reduce_rope_q_kernel(const float* __restrict__ P, int nch,
                                     const int* __restrict__ positions,
                                     const float* __restrict__ c4f, const float* __restrict__ s4f,
                                     float* __restrict__ qout) {
    int idx = blockIdx.x * 256 + threadIdx.x;   // 32768 threads
    int i = idx & 63, hh = (idx >> 6) & 15, b = idx >> 10;
    int base = b * HID + hh * DHEAD;
    float q1 = 0.f, q2 = 0.f;
    for (int c = 0; c < nch; ++c) {
        q1 += P[(size_t)c * (BATCH * HID) + base + i];
        q2 += P[(size_t)c * (BATCH * HID) + base + 64 + i];
    }
    int pos = positions[b];
    float co = c4f[pos * 64 + i], si = s4f[pos * 64 + i];
    qout[base + i]      = q1 * co - q2 * si;
    qout[base + 64 + i] = q1 * si + q2 * co;
}

// ---------------------------------------------------------------------------
// Flash-decode paged attention, stage 1. Block = (b,h,split); 8 token-streams
// (4 waves x 2 half-waves). Lane l5=lane&31 holds dims 4*l5..4*l5+3 (float4
// K/V loads). RoPE partner via shfl_xor(.,16); score reduce via 5 xor-shfls
// within the 32-lane half. 4-slot pipeline per stream. Online softmax.
// ---------------------------------------------------------------------------
__global__ __launch_bounds__(256) void attn_partial_kernel(
    const float* __restrict__ q, const float* __restrict__ kv,
    const int* __restrict__ block_tables, const int* __restrict__ context_lens,
    const float* __restrict__ c4f, const float* __restrict__ s4f,
    float* __restrict__ pm, float* __restrict__ pl, float* __restrict__ pacc) {
    const int idx = blockIdx.x;
    const int split = idx & (NSPLIT - 1);
    const int h = (idx >> 4) & 15;
    const int b = idx >> 8;
    const int wave = threadIdx.x >> 6, lane = threadIdx.x & 63, l5 = lane & 31;
    const int r = wave * 2 + (lane >> 5);      // stream id 0..7

    const int ctx = context_lens[b];
    const int s_begin = split * SPLIT_TOKENS;
    const int len = min(SPLIT_TOKENS, ctx - s_begin);

    __shared__ int bt[8];
    __shared__ float sm8[8], sl8[8];
    __shared__ float4 sacc[8][32];
    if (threadIdx.x < 8)
        bt[threadIdx.x] = block_tables[b * NBLK + split * 8 + threadIdx.x];
    __syncthreads();

    const float4 q4 = *reinterpret_cast<const float4*>(q + b * HID + h * DHEAD + 4 * l5);
    const float sgn = (l5 & 16) ? 1.f : -1.f;
    const int fq4 = (l5 & 15) * 4;

    float m = -INFINITY, l = 0.f;
    float4 a4 = make_float4(0.f, 0.f, 0.f, 0.f);

    if (len > 0) {
        const int nt = (len + 7) >> 3;
        const int NI = (nt + 3) & ~3;

        #define LOADT(T, K4, V4, C4, S4) {                                         \
            int tc = min((T), len - 1);                                            \
            const float* kp = kv + (size_t)bt[tc >> 4] * 65536                     \
                                 + (size_t)(tc & 15) * 2048 + h * DHEAD;           \
            K4 = *reinterpret_cast<const float4*>(kp + 4 * l5);                    \
            V4 = *reinterpret_cast<const float4*>(kp + 32768 + 4 * l5);            \
            C4 = *reinterpret_cast<const float4*>(c4f + (size_t)(s_begin + tc) * 64 + fq4); \
            float4 stmp = *reinterpret_cast<const float4*>(s4f + (size_t)(s_begin + tc) * 64 + fq4); \
            S4 = make_float4(stmp.x * sgn, stmp.y * sgn, stmp.z * sgn, stmp.w * sgn); \
        }

        #define PROCT(T, K4, V4, C4, S4) {                                         \
            float4 pk;                                                             \
            pk.x = __shfl_xor(K4.x, 16); pk.y = __shfl_xor(K4.y, 16);              \
            pk.z = __shfl_xor(K4.z, 16); pk.w = __shfl_xor(K4.w, 16);              \
            float krx = fmaf(pk.x, S4.x, K4.x * C4.x);                             \
            float kry = fmaf(pk.y, S4.y, K4.y * C4.y);                             \
            float krz = fmaf(pk.z, S4.z, K4.z * C4.z);                             \
            float krw = fmaf(pk.w, S4.w, K4.w * C4.w);                             \
            float dot = q4.x * krx + q4.y * kry + q4.z * krz + q4.w * krw;         \
            dot += __shfl_xor(dot, 1);  dot += __shfl_xor(dot, 2);                 \
            dot += __shfl_xor(dot, 4);  dot += __shfl_xor(dot, 8);                 \
            dot += __shfl_xor(dot, 16);                                            \
            float d = ((T) < len) ? dot * 0.08838834764831845f : -INFINITY;        \
            float mn = fmaxf(m, d);                                                \
            float ms = fmaxf(mn, -3.0e38f);                                        \
            float corr = __expf(m - ms);                                           \
            float e = __expf(d - ms);                                              \
            l = l * corr + e;                                                      \
            a4.x = fmaf(e, V4.x, a4.x * corr);                                     \
            a4.y = fmaf(e, V4.y, a4.y * corr);                                     \
            a4.z = fmaf(e, V4.z, a4.z * corr);                                     \
            a4.w = fmaf(e, V4.w, a4.w * corr);                                     \
            m = mn;                                                                \
        }

        float4 kA, vA, cA, sA, kB, vB, cB, sB;
        float4 kC, vC, cC, sC, kD, vD, cD, sD;
        LOADT(r,      kA, vA, cA, sA);
        LOADT(r + 8,  kB, vB, cB, sB);
        LOADT(r + 16, kC, vC, cC, sC);
        LOADT(r + 24, kD, vD, cD, sD);

        for (int i = 0; i < NI; i += 4) {
            int t = r + 8 * i;
            PROCT(t,      kA, vA, cA, sA);  LOADT(t + 32, kA, vA, cA, sA);
            PROCT(t + 8,  kB, vB, cB, sB);  LOADT(t + 40, kB, vB, cB, sB);
            PROCT(t + 16, kC, vC, cC, sC);  LOADT(t + 48, kC, vC, cC, sC);
            PROCT(t + 24, kD, vD, cD, sD);  LOADT(t + 56, kD, vD, cD, sD);
        }
        #undef LOADT
        #undef PROCT
    }

    if (l5 == 0) { sm8[r] = m; sl8[r] = l; }
    sacc[r][l5] = a4;
    __syncthreads();

    if (threadIdx.x < 32) {
        float M = -INFINITY;
        #pragma unroll
        for (int rr = 0; rr < 8; ++rr) M = fmaxf(M, sm8[rr]);
        float L = 0.f;
        float4 o = make_float4(0.f, 0.f, 0.f, 0.f);
        #pragma unroll
        for (int rr = 0; rr < 8; ++rr) {
            float ew = (sm8[rr] == -INFINITY) ? 0.f : __expf(sm8[rr] - M);
            L += sl8[rr] * ew;
            float4 v = sacc[rr][threadIdx.x];
            o.x = fmaf(v.x, ew, o.x); o.y = fmaf(v.y, ew, o.y);
            o.z = fmaf(v.z, ew, o.z); o.w = fmaf(v.w, ew, o.w);
        }
        if (threadIdx.x == 0) { pm[idx] = M; pl[idx] = L; }
        *reinterpret_cast<float4*>(pacc + (size_t)idx * 128 + 4 * threadIdx.x) = o;
    }
}

// ---------------------------------------------------------------------------
// Flash-decode stage 2: combine NSPLIT partials per (b,h).
// ---------------------------------------------------------------------------
__global__ void attn_combine_kernel(const float* __restrict__ pm, const float* __restrict__ pl,
                                    const float* __restrict__ pacc, float* __restrict__ attn_out) {
    const int bh = blockIdx.x;
    const int l5 = threadIdx.x;
    if (l5 >= 32) return;
    const int base = bh * NSPLIT;
    float M = -INFINITY;
    #pragma unroll
    for (int sp = 0; sp < NSPLIT; ++sp) M = fmaxf(M, pm[base + sp]);
    float L = 0.f;
    float4 o = make_float4(0.f, 0.f, 0.f, 0.f);
    #pragma unroll
    for (int sp = 0; sp < NSPLIT; ++sp) {
        float mv = pm[base + sp];
        float ew = (mv == -INFINITY) ? 0.f : __expf(mv - M);
        L += pl[base + sp] * ew;
        float4 v = *reinterpret_cast<const float4*>(pacc + (size_t)(base + sp) * 128 + 4 * l5);
        o.x = fmaf(v.x, ew, o.x); o.y = fmaf(v.y, ew, o.y);
        o.z = fmaf(v.z, ew, o.z); o.w = fmaf(v.w, ew, o.w);
    }
    float inv = 1.f / L;
    *reinterpret_cast<float4*>(attn_out + bh * 128 + 4 * l5) =
        make_float4(o.x * inv, o.y * inv, o.z * inv, o.w * inv);
}

// ---------------------------------------------------------------------------
extern "C" void kernel_launch(void* const* d_in, const int* in_sizes, int n_in,
                              void* d_out, int out_size, void* d_ws, size_t ws_size,
                              hipStream_t stream) {
    const int*   input_ids    = (const int*)d_in[0];
    const int*   positions    = (const int*)d_in[1];
    const float* kv_cache     = (const float*)d_in[2];
    const int*   block_tables = (const int*)d_in[3];
    const int*   context_lens = (const int*)d_in[4];
    const float* embed_tokens = (const float*)d_in[5];
    const float* embed_pos    = (const float*)d_in[6];
    const float* Wq  = (const float*)d_in[7];
    const float* Wo  = (const float*)d_in[8];
    const float* Wprm= (const float*)d_in[9];
    const float* W1  = (const float*)d_in[10];
    const float* W2  = (const float*)d_in[11];
    float* out = (float*)d_out;

    char* ws = (char*)d_ws;
    size_t off = 0;
    float* c4f  = (float*)(ws + off); off += (size_t)KV_LEN * 64 * 4;     // 512 KB
    float* s4f  = (float*)(ws + off); off += (size_t)KV_LEN * 64 * 4;     // 512 KB
    float* emb  = (float*)(ws + off); off += (size_t)BATCH * HID * 4;     // 256 KB
    float* qbuf = (float*)(ws + off); off += (size_t)BATCH * HID * 4;
    float* attn = (float*)(ws + off); off += (size_t)BATCH * HID * 4;
    float* ao   = (float*)(ws + off); off += (size_t)BATCH * HID * 4;
    float* h1   = (float*)(ws + off); off += (size_t)BATCH * FFN * 4;     // 1 MB
    float* pm   = (float*)(ws + off); off += (size_t)BATCH * HEADS * NSPLIT * 4;
    float* plv  = (float*)(ws + off); off += (size_t)BATCH * HEADS * NSPLIT * 4;
    float* pacc = (float*)(ws + off); off += (size_t)BATCH * HEADS * NSPLIT * 128 * 4; // 4 MB
    float* P    = (float*)(ws + off); off += (size_t)64 * BATCH * FFN * 4;  // 67 MB (max partials)
    float* Pprm = (float*)(ws + off); off += (size_t)64 * BATCH * HID * 4;  // 16.8 MB
    (void)ws_size; (void)in_sizes; (void)n_in; (void)out_size;

    // 1. RoPE tables + embeddings
    prep_kernel<<<544, 256, 0, stream>>>(input_ids, positions, embed_tokens, embed_pos,
                                         c4f, s4f, emb);
    // 2. q = emb @ Wq  (SK=64, KC=32) -> RoPE
    gemm_partial<32><<<dim3(2, 64), 256, 0, stream>>>(emb, Wq, P, HID, HID);
    reduce_rope_q_kernel<<<128, 256, 0, stream>>>(P, 64, positions, c4f, s4f, qbuf);
    // 3. paged attention (flash-decode: 16 splits + combine)
    attn_partial_kernel<<<BATCH * HEADS * NSPLIT, 256, 0, stream>>>(
        qbuf, kv_cache, block_tables, context_lens, c4f, s4f, pm, plv, pacc);
    attn_combine_kernel<<<BATCH * HEADS, 64, 0, stream>>>(pm, plv, pacc, attn);
    // 4. ao = attn @ Wo  (SK=64)
    gemm_partial<32><<<dim3(2, 64), 256, 0, stream>>>(attn, Wo, P, HID, HID);
    reduce4_kernel<<<64, 256, 0, stream>>>(P, 64, BATCH * HID / 4, ao);
    // 5. prm partials = ao @ Wprm  (SK=64; reduced in the final kernel)
    gemm_partial<32><<<dim3(2, 64), 256, 0, stream>>>(ao, Wprm, Pprm, HID, HID);
    // 6. h1 = ao @ W1  (SK=32, KC=64)
    gemm_partial<64><<<dim3(8, 32), 256, 0, stream>>>(ao, W1, P, HID, FFN);
    reduce4_kernel<<<256, 256, 0, stream>>>(P, 32, BATCH * FFN / 4, h1);
    // 7. out = h1 @ W2 + prm  (SK=64, KC=128)
    gemm_partial<128><<<dim3(2, 64), 256, 0, stream>>>(h1, W2, P, FFN, HID);
    reduce4_dual_kernel<<<64, 256, 0, stream>>>(P, 64, Pprm, 64, BATCH * HID / 4, out);
}

// Round 5
// 294.928 us; speedup vs baseline: 2.3761x; 1.2414x over previous
//
#include <hip/hip_runtime.h>
#include <hip/hip_bf16.h>
#include <math.h>

// Problem constants (from reference)
#define BATCH   32
#define NBLK    128
#define BLOCK_T 16
#define HEADS   16
#define DHEAD   128
#define HID     2048
#define FFN     8192
#define KV_LEN  2048

#define NSPLIT  16
#define SPLIT_TOKENS 128

// ---------------------------------------------------------------------------
// prep: RoPE cos/sin tables (scalar layout [tok][64], freq-major) + embeddings
// ---------------------------------------------------------------------------
__global__ void prep_kernel(const int* __restrict__ ids, const int* __restrict__ pos,
                            const float* __restrict__ et, const float* __restrict__ ep,
                            float* __restrict__ c4f, float* __restrict__ s4f,
                            float* __restrict__ emb) {
    if (blockIdx.x < 512) {
        int s = blockIdx.x * 4 + (threadIdx.x >> 6);   // 0..2047
        int i = threadIdx.x & 63;
        float inv = powf(10000.0f, -(float)i / 64.0f);
        float ang = (float)s * inv;
        c4f[s * 64 + i] = cosf(ang);
        s4f[s * 64 + i] = sinf(ang);
    } else {
        int b = blockIdx.x - 512;
        int id = ids[b], p = pos[b];
        const float4* a = (const float4*)(et + (size_t)id * HID);
        const float4* d = (const float4*)(ep + (size_t)p * HID);
        float4* o = (float4*)(emb + (size_t)b * HID);
        for (int c = threadIdx.x; c < HID / 4; c += 256) {
            float4 x = a[c], y = d[c];
            o[c] = make_float4(x.x + y.x, x.y + y.y, x.z + y.z, x.w + y.w);
        }
    }
}

// ---------------------------------------------------------------------------
// Split-K skinny GEMM body: X[32][K] @ W[K][N] -> P[chunk][32][N] partials.
// Thread: 2 consecutive cols (float2 W loads), all 32 batch rows.
// 16-deep double-buffered prefetch (8 KB/wave in flight). 512 cols per block.
// ---------------------------------------------------------------------------
template <int KC>
__device__ __forceinline__ void gemm2_body(
    const float* __restrict__ X, const float* __restrict__ W,
    float* __restrict__ P, int K, int N, int bx, int by, int tid) {
    __shared__ float xs[KC][36];          // xs[k][batch], 144B rows (16B-aligned)
    const int k0 = by * KC;
    const int j  = bx * 512 + tid * 2;

    #pragma unroll
    for (int t = tid; t < 32 * KC / 4; t += 256) {
        int bb = t / (KC / 4), qq = t % (KC / 4);
        float4 xv = *reinterpret_cast<const float4*>(X + (size_t)bb * K + k0 + 4 * qq);
        xs[4 * qq + 0][bb] = xv.x; xs[4 * qq + 1][bb] = xv.y;
        xs[4 * qq + 2][bb] = xv.z; xs[4 * qq + 3][bb] = xv.w;
    }
    __syncthreads();

    float acc[32][2];
    #pragma unroll
    for (int bb = 0; bb < 32; ++bb) { acc[bb][0] = 0.f; acc[bb][1] = 0.f; }

    const float* wp = W + (size_t)k0 * N + j;
    float2 bufA[16], bufB[16];
    #pragma unroll
    for (int u = 0; u < 16; ++u)
        bufA[u] = *reinterpret_cast<const float2*>(wp + (size_t)u * N);

    #define G2_FMA16(BUF, KK)                                                   \
        _Pragma("unroll")                                                       \
        for (int u = 0; u < 16; ++u) {                                          \
            const float2 w = BUF[u];                                            \
            _Pragma("unroll")                                                   \
            for (int g = 0; g < 8; ++g) {                                       \
                const float4 xv = *reinterpret_cast<const float4*>(&xs[(KK) + u][g * 4]); \
                acc[4*g+0][0] = fmaf(xv.x, w.x, acc[4*g+0][0]);                 \
                acc[4*g+0][1] = fmaf(xv.x, w.y, acc[4*g+0][1]);                 \
                acc[4*g+1][0] = fmaf(xv.y, w.x, acc[4*g+1][0]);                 \
                acc[4*g+1][1] = fmaf(xv.y, w.y, acc[4*g+1][1]);                 \
                acc[4*g+2][0] = fmaf(xv.z, w.x, acc[4*g+2][0]);                 \
                acc[4*g+2][1] = fmaf(xv.z, w.y, acc[4*g+2][1]);                 \
                acc[4*g+3][0] = fmaf(xv.w, w.x, acc[4*g+3][0]);                 \
                acc[4*g+3][1] = fmaf(xv.w, w.y, acc[4*g+3][1]);                 \
            }                                                                   \
        }

    for (int kk = 0; kk < KC; kk += 32) {
        #pragma unroll
        for (int u = 0; u < 16; ++u)
            bufB[u] = *reinterpret_cast<const float2*>(wp + (size_t)(kk + 16 + u) * N);
        G2_FMA16(bufA, kk)
        #pragma unroll
        for (int u = 0; u < 16; ++u) {
            int rr = kk + 32 + u; rr = (rr < KC) ? rr : (KC - 1);
            bufA[u] = *reinterpret_cast<const float2*>(wp + (size_t)rr * N);
        }
        G2_FMA16(bufB, kk + 16)
    }
    #undef G2_FMA16

    float* pp = P + ((size_t)by * 32) * N + j;
    #pragma unroll
    for (int bb = 0; bb < 32; ++bb)
        *reinterpret_cast<float2*>(pp + (size_t)bb * N) = make_float2(acc[bb][0], acc[bb][1]);
}

// standalone gemm2: grid (Nsplit, SK)
template <int KC>
__global__ __launch_bounds__(256) void gemm2_kernel(
    const float* __restrict__ X, const float* __restrict__ W,
    float* __restrict__ P, int K, int N) {
    gemm2_body<KC>(X, W, P, K, N, blockIdx.x, blockIdx.y, threadIdx.x);
}

// merged: blocks 0..255 -> ao@Wprm (Nsplit=4, SK=64); 256..511 -> ao@W1 (Nsplit=16, SK=16)
__global__ __launch_bounds__(256) void gemm2_dual_kernel(
    const float* __restrict__ X, const float* __restrict__ Wprm,
    const float* __restrict__ W1,
    float* __restrict__ Pprm, float* __restrict__ P1) {
    if (blockIdx.x < 256) {
        gemm2_body<32>(X, Wprm, Pprm, HID, HID, blockIdx.x & 3, blockIdx.x >> 2, threadIdx.x);
    } else {
        int bb = blockIdx.x - 256;
        gemm2_body<128>(X, W1, P1, HID, FFN, bb & 15, bb >> 4, threadIdx.x);
    }
}

// ---------------------------------------------------------------------------
// Two-stage partial reduction.
// stage1: grid (total4/256, ngroups); group g sums 8 chunks -> S[g][total4]
//         groups [0,ngA) read PA, groups [ngA, ...) read PB.
// stage2: sum S groups -> out.
// ---------------------------------------------------------------------------
__global__ void red_stage1(const float* __restrict__ PA, const float* __restrict__ PB,
                           int ngA, float* __restrict__ S, int total4) {
    int idx4 = blockIdx.x * 256 + threadIdx.x;
    if (idx4 >= total4) return;
    int g = blockIdx.y;
    const float4* src = (const float4*)((g < ngA) ? PA : PB);
    int c0 = ((g < ngA) ? g : (g - ngA)) * 8;
    float4 s = make_float4(0.f, 0.f, 0.f, 0.f);
    #pragma unroll
    for (int c = 0; c < 8; ++c) {
        float4 v = src[(size_t)(c0 + c) * total4 + idx4];
        s.x += v.x; s.y += v.y; s.z += v.z; s.w += v.w;
    }
    ((float4*)S)[(size_t)g * total4 + idx4] = s;
}

__global__ void red_stage2(const float* __restrict__ S, int ng, int total4,
                           float* __restrict__ out) {
    int idx4 = blockIdx.x * 256 + threadIdx.x;
    if (idx4 >= total4) return;
    float4 s = make_float4(0.f, 0.f, 0.f, 0.f);
    for (int g = 0; g < ng; ++g) {
        float4 v = ((const float4*)S)[(size_t)g * total4 + idx4];
        s.x += v.x; s.y += v.y; s.z += v.z; s.w += v.w;
    }
    ((float4*)out)[idx4] = s;
}

// single-stage reduce (few chunks): out[idx4] = sum_c P[c][idx4]
__global__ void reduce4_kernel(const float* __restrict__ P, int nch, int total4,
                               float* __restrict__ out) {
    int idx4 = blockIdx.x * 256 + threadIdx.x;
    if (idx4 >= total4) return;
    const float4* P4 = (const float4*)P;
    float4 s = make_float4(0.f, 0.f, 0.f, 0.f);
    for (int c = 0; c < nch; ++c) {
        float4 v = P4[(size_t)c * total4 + idx4];
        s.x += v.x; s.y += v.y; s.z += v.z; s.w += v.w;
    }
    ((float4*)out)[idx4] = s;
}

// ---------------------------------------------------------------------------
// Final Wq reduce (from S groups) + RoPE -> q[32][2048]
// ---------------------------------------------------------------------------
__global__ void rope_q_from_S(const float* __restrict__ S, int ng,
                              const int* __restrict__ positions,
                              const float* __restrict__ c4f, const float* __restrict__ s4f,
                              float* __restrict__ qout) {
    int idx = blockIdx.x * 256 + threadIdx.x;   // 32768 threads
    int i = idx & 63, hh = (idx >> 6) & 15, b = idx >> 10;
    int base = b * HID + hh * DHEAD;
    float q1 = 0.f, q2 = 0.f;
    for (int g = 0; g < ng; ++g) {
        q1 += S[(size_t)g * (BATCH * HID) + base + i];
        q2 += S[(size_t)g * (BATCH * HID) + base + 64 + i];
    }
    int pos = positions[b];
    float co = c4f[pos * 64 + i], si = s4f[pos * 64 + i];
    qout[base + i]      = q1 * co - q2 * si;
    qout[base + 64 + i] = q1 * si + q2 * co;
}

// ---------------------------------------------------------------------------
// Flash-decode paged attention, stage 1. Block = (b,h,split); 8 token-streams
// (4 waves x 2 half-waves). Lane l5=lane&31 holds dims 4*l5..4*l5+3 (float4
// K/V loads). RoPE partner via shfl_xor(.,16); score reduce via 5 xor-shfls
// within the 32-lane half. 4-slot pipeline per stream. Online softmax.
// ---------------------------------------------------------------------------
__global__ __launch_bounds__(256) void attn_partial_kernel(
    const float* __restrict__ q, const float* __restrict__ kv,
    const int* __restrict__ block_tables, const int* __restrict__ context_lens,
    const float* __restrict__ c4f, const float* __restrict__ s4f,
    float* __restrict__ pm, float* __restrict__ pl, float* __restrict__ pacc) {
    const int idx = blockIdx.x;
    const int split = idx & (NSPLIT - 1);
    const int h = (idx >> 4) & 15;
    const int b = idx >> 8;
    const int wave = threadIdx.x >> 6, lane = threadIdx.x & 63, l5 = lane & 31;
    const int r = wave * 2 + (lane >> 5);      // stream id 0..7

    const int ctx = context_lens[b];
    const int s_begin = split * SPLIT_TOKENS;
    const int len = min(SPLIT_TOKENS, ctx - s_begin);

    __shared__ int bt[8];
    __shared__ float sm8[8], sl8[8];
    __shared__ float4 sacc[8][32];
    if (threadIdx.x < 8)
        bt[threadIdx.x] = block_tables[b * NBLK + split * 8 + threadIdx.x];
    __syncthreads();

    const float4 q4 = *reinterpret_cast<const float4*>(q + b * HID + h * DHEAD + 4 * l5);
    const float sgn = (l5 & 16) ? 1.f : -1.f;
    const int fq4 = (l5 & 15) * 4;

    float m = -INFINITY, l = 0.f;
    float4 a4 = make_float4(0.f, 0.f, 0.f, 0.f);

    if (len > 0) {
        const int nt = (len + 7) >> 3;
        const int NI = (nt + 3) & ~3;

        #define LOADT(T, K4, V4, C4, S4) {                                         \
            int tc = min((T), len - 1);                                            \
            const float* kp = kv + (size_t)bt[tc >> 4] * 65536                     \
                                 + (size_t)(tc & 15) * 2048 + h * DHEAD;           \
            K4 = *reinterpret_cast<const float4*>(kp + 4 * l5);                    \
            V4 = *reinterpret_cast<const float4*>(kp + 32768 + 4 * l5);            \
            C4 = *reinterpret_cast<const float4*>(c4f + (size_t)(s_begin + tc) * 64 + fq4); \
            float4 stmp = *reinterpret_cast<const float4*>(s4f + (size_t)(s_begin + tc) * 64 + fq4); \
            S4 = make_float4(stmp.x * sgn, stmp.y * sgn, stmp.z * sgn, stmp.w * sgn); \
        }

        #define PROCT(T, K4, V4, C4, S4) {                                         \
            float4 pk;                                                             \
            pk.x = __shfl_xor(K4.x, 16); pk.y = __shfl_xor(K4.y, 16);              \
            pk.z = __shfl_xor(K4.z, 16); pk.w = __shfl_xor(K4.w, 16);              \
            float krx = fmaf(pk.x, S4.x, K4.x * C4.x);                             \
            float kry = fmaf(pk.y, S4.y, K4.y * C4.y);                             \
            float krz = fmaf(pk.z, S4.z, K4.z * C4.z);                             \
            float krw = fmaf(pk.w, S4.w, K4.w * C4.w);                             \
            float dot = q4.x * krx + q4.y * kry + q4.z * krz + q4.w * krw;         \
            dot += __shfl_xor(dot, 1);  dot += __shfl_xor(dot, 2);                 \
            dot += __shfl_xor(dot, 4);  dot += __shfl_xor(dot, 8);                 \
            dot += __shfl_xor(dot, 16);                                            \
            float d = ((T) < len) ? dot * 0.08838834764831845f : -INFINITY;        \
            float mn = fmaxf(m, d);                                                \
            float ms = fmaxf(mn, -3.0e38f);                                        \
            float corr = __expf(m - ms);                                           \
            float e = __expf(d - ms);                                              \
            l = l * corr + e;                                                      \
            a4.x = fmaf(e, V4.x, a4.x * corr);                                     \
            a4.y = fmaf(e, V4.y, a4.y * corr);                                     \
            a4.z = fmaf(e, V4.z, a4.z * corr);                                     \
            a4.w = fmaf(e, V4.w, a4.w * corr);                                     \
            m = mn;                                                                \
        }

        float4 kA, vA, cA, sA, kB, vB, cB, sB;
        float4 kC, vC, cC, sC, kD, vD, cD, sD;
        LOADT(r,      kA, vA, cA, sA);
        LOADT(r + 8,  kB, vB, cB, sB);
        LOADT(r + 16, kC, vC, cC, sC);
        LOADT(r + 24, kD, vD, cD, sD);

        for (int i = 0; i < NI; i += 4) {
            int t = r + 8 * i;
            PROCT(t,      kA, vA, cA, sA);  LOADT(t + 32, kA, vA, cA, sA);
            PROCT(t + 8,  kB, vB, cB, sB);  LOADT(t + 40, kB, vB, cB, sB);
            PROCT(t + 16, kC, vC, cC, sC);  LOADT(t + 48, kC, vC, cC, sC);
            PROCT(t + 24, kD, vD, cD, sD);  LOADT(t + 56, kD, vD, cD, sD);
        }
        #undef LOADT
        #undef PROCT
    }

    if (l5 == 0) { sm8[r] = m; sl8[r] = l; }
    sacc[r][l5] = a4;
    __syncthreads();

    if (threadIdx.x < 32) {
        float M = -INFINITY;
        #pragma unroll
        for (int rr = 0; rr < 8; ++rr) M = fmaxf(M, sm8[rr]);
        float L = 0.f;
        float4 o = make_float4(0.f, 0.f, 0.f, 0.f);
        #pragma unroll
        for (int rr = 0; rr < 8; ++rr) {
            float ew = (sm8[rr] == -INFINITY) ? 0.f : __expf(sm8[rr] - M);
            L += sl8[rr] * ew;
            float4 v = sacc[rr][threadIdx.x];
            o.x = fmaf(v.x, ew, o.x); o.y = fmaf(v.y, ew, o.y);
            o.z = fmaf(v.z, ew, o.z); o.w = fmaf(v.w, ew, o.w);
        }
        if (threadIdx.x == 0) { pm[idx] = M; pl[idx] = L; }
        *reinterpret_cast<float4*>(pacc + (size_t)idx * 128 + 4 * threadIdx.x) = o;
    }
}

// ---------------------------------------------------------------------------
// Flash-decode stage 2: combine NSPLIT partials per (b,h).
// ---------------------------------------------------------------------------
__global__ void attn_combine_kernel(const float* __restrict__ pm, const float* __restrict__ pl,
                                    const float* __restrict__ pacc, float* __restrict__ attn_out) {
    const int bh = blockIdx.x;
    const int l5 = threadIdx.x;
    if (l5 >= 32) return;
    const int base = bh * NSPLIT;
    float M = -INFINITY;
    #pragma unroll
    for (int sp = 0; sp < NSPLIT; ++sp) M = fmaxf(M, pm[base + sp]);
    float L = 0.f;
    float4 o = make_float4(0.f, 0.f, 0.f, 0.f);
    #pragma unroll
    for (int sp = 0; sp < NSPLIT; ++sp) {
        float mv = pm[base + sp];
        float ew = (mv == -INFINITY) ? 0.f : __expf(mv - M);
        L += pl[base + sp] * ew;
        float4 v = *reinterpret_cast<const float4*>(pacc + (size_t)(base + sp) * 128 + 4 * l5);
        o.x = fmaf(v.x, ew, o.x); o.y = fmaf(v.y, ew, o.y);
        o.z = fmaf(v.z, ew, o.z); o.w = fmaf(v.w, ew, o.w);
    }
    float inv = 1.f / L;
    *reinterpret_cast<float4*>(attn_out + bh * 128 + 4 * l5) =
        make_float4(o.x * inv, o.y * inv, o.z * inv, o.w * inv);
}

// ---------------------------------------------------------------------------
extern "C" void kernel_launch(void* const* d_in, const int* in_sizes, int n_in,
                              void* d_out, int out_size, void* d_ws, size_t ws_size,
                              hipStream_t stream) {
    const int*   input_ids    = (const int*)d_in[0];
    const int*   positions    = (const int*)d_in[1];
    const float* kv_cache     = (const float*)d_in[2];
    const int*   block_tables = (const int*)d_in[3];
    const int*   context_lens = (const int*)d_in[4];
    const float* embed_tokens = (const float*)d_in[5];
    const float* embed_pos    = (const float*)d_in[6];
    const float* Wq  = (const float*)d_in[7];
    const float* Wo  = (const float*)d_in[8];
    const float* Wprm= (const float*)d_in[9];
    const float* W1  = (const float*)d_in[10];
    const float* W2  = (const float*)d_in[11];
    float* out = (float*)d_out;

    char* ws = (char*)d_ws;
    size_t off = 0;
    float* c4f  = (float*)(ws + off); off += (size_t)KV_LEN * 64 * 4;     // 512 KB
    float* s4f  = (float*)(ws + off); off += (size_t)KV_LEN * 64 * 4;     // 512 KB
    float* emb  = (float*)(ws + off); off += (size_t)BATCH * HID * 4;     // 256 KB
    float* qbuf = (float*)(ws + off); off += (size_t)BATCH * HID * 4;
    float* attn = (float*)(ws + off); off += (size_t)BATCH * HID * 4;
    float* ao   = (float*)(ws + off); off += (size_t)BATCH * HID * 4;
    float* h1   = (float*)(ws + off); off += (size_t)BATCH * FFN * 4;     // 1 MB
    float* pm   = (float*)(ws + off); off += (size_t)BATCH * HEADS * NSPLIT * 4;
    float* plv  = (float*)(ws + off); off += (size_t)BATCH * HEADS * NSPLIT * 4;
    float* pacc = (float*)(ws + off); off += (size_t)BATCH * HEADS * NSPLIT * 128 * 4; // 4 MB
    float* S    = (float*)(ws + off); off += (size_t)16 * BATCH * HID * 4;  // 4.2 MB stage-1 sums
    float* P    = (float*)(ws + off); off += (size_t)64 * BATCH * FFN * 4;  // P partials (max 67 MB)
    float* Pprm = (float*)(ws + off); off += (size_t)64 * BATCH * HID * 4;  // 16.8 MB
    (void)ws_size; (void)in_sizes; (void)n_in; (void)out_size;

    const int T4_HID = BATCH * HID / 4;   // 16384
    const int T4_FFN = BATCH * FFN / 4;   // 65536

    // 1. RoPE tables + embeddings
    prep_kernel<<<544, 256, 0, stream>>>(input_ids, positions, embed_tokens, embed_pos,
                                         c4f, s4f, emb);
    // 2. q = emb @ Wq  (Nsplit=4, SK=64, KC=32) -> 2-stage reduce + RoPE
    gemm2_kernel<32><<<dim3(4, 64), 256, 0, stream>>>(emb, Wq, P, HID, HID);
    red_stage1<<<dim3(64, 8), 256, 0, stream>>>(P, P, 8, S, T4_HID);
    rope_q_from_S<<<128, 256, 0, stream>>>(S, 8, positions, c4f, s4f, qbuf);
    // 3. paged attention (flash-decode: 16 splits + combine)
    attn_partial_kernel<<<BATCH * HEADS * NSPLIT, 256, 0, stream>>>(
        qbuf, kv_cache, block_tables, context_lens, c4f, s4f, pm, plv, pacc);
    attn_combine_kernel<<<BATCH * HEADS, 64, 0, stream>>>(pm, plv, pacc, attn);
    // 4. ao = attn @ Wo  (Nsplit=4, SK=64)
    gemm2_kernel<32><<<dim3(4, 64), 256, 0, stream>>>(attn, Wo, P, HID, HID);
    red_stage1<<<dim3(64, 8), 256, 0, stream>>>(P, P, 8, S, T4_HID);
    red_stage2<<<64, 256, 0, stream>>>(S, 8, T4_HID, ao);
    // 5. Pprm = ao @ Wprm  ||  P = ao @ W1   (one 512-block launch)
    gemm2_dual_kernel<<<512, 256, 0, stream>>>(ao, Wprm, W1, Pprm, P);
    // 6. h1 = reduce16(P)  (SK=16, 256-block single stage)
    reduce4_kernel<<<256, 256, 0, stream>>>(P, 16, T4_FFN, h1);
    // 7. out = h1 @ W2 + prm  (Nsplit=4, SK=64, KC=128; shared 2-stage reduce)
    gemm2_kernel<128><<<dim3(4, 64), 256, 0, stream>>>(h1, W2, P, FFN, HID);
    red_stage1<<<dim3(64, 16), 256, 0, stream>>>(P, Pprm, 8, S, T4_HID);
    red_stage2<<<64, 256, 0, stream>>>(S, 16, T4_HID, out);
}